// Round 6
// baseline (450.423 us; speedup 1.0000x reference)
//
#include <hip/hip_runtime.h>
#include <hip/hip_bf16.h>

typedef __bf16 bf16x8 __attribute__((ext_vector_type(8)));
typedef float f32x4 __attribute__((ext_vector_type(4)));
typedef short short4v __attribute__((ext_vector_type(4)));
typedef unsigned short ushort8v __attribute__((ext_vector_type(8)));

#define DEV static __device__ __forceinline__

#if __has_builtin(__builtin_amdgcn_exp2f)
#define EXP2(x) __builtin_amdgcn_exp2f(x)
#else
#define EXP2(x) exp2f(x)
#endif

DEV unsigned short f2bf(float x) {
  union { __hip_bfloat16 b; unsigned short u; } c;
  c.b = __float2bfloat16(x);
  return c.u;
}

// fast RNE f32->bf16 (inputs are finite; no NaN path needed)
DEV unsigned short f2bf_fast(float x) {
  union { float f; unsigned u; } c;
  c.f = x;
  unsigned u = c.u + 0x7fff + ((c.u >> 16) & 1);
  return (unsigned short)(u >> 16);
}

DEV void gload_lds16(const void* g, void* l) {
  __builtin_amdgcn_global_load_lds((const __attribute__((address_space(1))) void*)g,
                                   (__attribute__((address_space(3))) void*)l, 16, 0, 0);
}

// ---------- convert q/k/v fp32 -> bf16 ----------
__global__ __launch_bounds__(256) void cvt_qkv(const float* __restrict__ q,
                                               const float* __restrict__ k,
                                               const float* __restrict__ v,
                                               unsigned short* __restrict__ qb,
                                               unsigned short* __restrict__ kb,
                                               unsigned short* __restrict__ vb) {
  const float* src = blockIdx.y == 0 ? q : (blockIdx.y == 1 ? k : v);
  unsigned short* dst = blockIdx.y == 0 ? qb : (blockIdx.y == 1 ? kb : vb);
  int idx = (blockIdx.x * 256 + threadIdx.x) * 4;
  float4 xv = *(const float4*)(src + idx);
  ushort4 o;
  o.x = f2bf(xv.x); o.y = f2bf(xv.y); o.z = f2bf(xv.z); o.w = f2bf(xv.w);
  *(ushort4*)(dst + idx) = o;
}

// ---------- transpose 4x 1024x1024 weight fp32 -> bf16 (Wt[n][k] = W[k][n]) ----------
__global__ __launch_bounds__(256) void transpose_all(const float* __restrict__ W0,
                                                     const float* __restrict__ W1,
                                                     const float* __restrict__ W2,
                                                     const float* __restrict__ W3,
                                                     unsigned short* __restrict__ T0,
                                                     unsigned short* __restrict__ T1,
                                                     unsigned short* __restrict__ T2,
                                                     unsigned short* __restrict__ T3) {
  __shared__ float t[64][68];
  int sel = blockIdx.x >> 8;
  const float* W = sel == 0 ? W0 : sel == 1 ? W1 : sel == 2 ? W2 : W3;
  unsigned short* Wt = sel == 0 ? T0 : sel == 1 ? T1 : sel == 2 ? T2 : T3;
  int tile = blockIdx.x & 255;
  int tr = tile >> 4, tc = tile & 15;
  int lr = threadIdx.x >> 4, lc4 = threadIdx.x & 15;
#pragma unroll
  for (int i = 0; i < 4; ++i) {
    int r = i * 16 + lr;
    float4 v = *(const float4*)(W + (size_t)(tr * 64 + r) * 1024 + tc * 64 + lc4 * 4);
    t[r][lc4 * 4 + 0] = v.x; t[r][lc4 * 4 + 1] = v.y;
    t[r][lc4 * 4 + 2] = v.z; t[r][lc4 * 4 + 3] = v.w;
  }
  __syncthreads();
#pragma unroll
  for (int i = 0; i < 4; ++i) {
    int r = i * 16 + lr;
    ushort4 o;
    o.x = f2bf(t[lc4 * 4 + 0][r]);
    o.y = f2bf(t[lc4 * 4 + 1][r]);
    o.z = f2bf(t[lc4 * 4 + 2][r]);
    o.w = f2bf(t[lc4 * 4 + 3][r]);
    *(ushort4*)(Wt + (size_t)(tc * 64 + r) * 1024 + tr * 64 + lc4 * 4) = o;
  }
}

// ---------- GEMM core: C[4096,1024] = A[4096,1024] @ Bt[1024,1024]^T + bias, *scale ----------
DEV void gemm_core(const unsigned short* __restrict__ A, const unsigned short* __restrict__ Bt,
                   const float* __restrict__ bias, void* __restrict__ Cout,
                   float scale, int mode, int blk,
                   unsigned short* As, unsigned short* Bs) {
  const int tid = threadIdx.x;
  const int l = tid & 63, w = tid >> 6;
  const int wm = w >> 1, wn = w & 1;
  const int r15 = l & 15, kg = l >> 4;
  const int mt = blk >> 3, nt = blk & 7;

  const f32x4 fz = {0.f, 0.f, 0.f, 0.f};
  f32x4 acc[4][4];
#pragma unroll
  for (int i = 0; i < 4; ++i)
#pragma unroll
    for (int j = 0; j < 4; ++j) acc[i][j] = fz;

  for (int kt = 0; kt < 16; ++kt) {
#pragma unroll
    for (int c = 0; c < 4; ++c) {
      int chunk = c * 256 + tid;
      int row = chunk >> 3, slot = chunk & 7;
      int gsl = slot ^ (row & 7);
      gload_lds16(A + (size_t)(mt * 128 + row) * 1024 + kt * 64 + gsl * 8, As + chunk * 8);
      gload_lds16(Bt + (size_t)(nt * 128 + row) * 1024 + kt * 64 + gsl * 8, Bs + chunk * 8);
    }
    __syncthreads();
#pragma unroll
    for (int ks = 0; ks < 2; ++ks) {
      bf16x8 a[4], b[4];
      int slot = ks * 4 + kg;
#pragma unroll
      for (int i = 0; i < 4; ++i) {
        int ra = wm * 64 + i * 16 + r15;
        a[i] = *(const bf16x8*)(As + ra * 64 + (slot ^ (ra & 7)) * 8);
        int rb = wn * 64 + i * 16 + r15;
        b[i] = *(const bf16x8*)(Bs + rb * 64 + (slot ^ (rb & 7)) * 8);
      }
#pragma unroll
      for (int i = 0; i < 4; ++i)
#pragma unroll
        for (int j = 0; j < 4; ++j)
          acc[i][j] = __builtin_amdgcn_mfma_f32_16x16x32_bf16(a[i], b[j], acc[i][j], 0, 0, 0);
    }
    __syncthreads();
  }

#pragma unroll
  for (int j = 0; j < 4; ++j) {
    int gc = nt * 128 + wn * 64 + j * 16 + r15;
    float bj = bias[gc];
#pragma unroll
    for (int i = 0; i < 4; ++i) {
#pragma unroll
      for (int r = 0; r < 4; ++r) {
        int gr = mt * 128 + wm * 64 + i * 16 + kg * 4 + r;
        float val = (acc[i][j][r] + bj) * scale;
        if (mode == 2) {
          ((float*)Cout)[(size_t)gr * 1024 + gc] = val;
        } else {
          int bb = gr >> 11, s = gr & 2047, hh = gc >> 6, dk = gc & 63;
          if (mode == 0)
            ((unsigned short*)Cout)[((size_t)(bb * 16 + hh) * 2048 + s) * 64 + dk] = f2bf(val);
          else
            ((unsigned short*)Cout)[((size_t)(bb * 16 + hh) * 64 + dk) * 2048 + s] = f2bf(val);
        }
      }
    }
  }
}

__global__ __launch_bounds__(256) void gemm_qkv(const unsigned short* __restrict__ qb,
                                                const unsigned short* __restrict__ kb,
                                                const unsigned short* __restrict__ vb,
                                                const unsigned short* __restrict__ Wtq,
                                                const unsigned short* __restrict__ Wtk,
                                                const unsigned short* __restrict__ Wtv,
                                                const float* __restrict__ bq,
                                                const float* __restrict__ bk,
                                                const float* __restrict__ bv,
                                                unsigned short* __restrict__ Qh,
                                                unsigned short* __restrict__ Kh,
                                                unsigned short* __restrict__ Vt) {
  __shared__ unsigned short As[128 * 64];
  __shared__ unsigned short Bs[128 * 64];
  int sel = blockIdx.x >> 8, blk = blockIdx.x & 255;
  const unsigned short* A = sel == 0 ? qb : sel == 1 ? kb : vb;
  const unsigned short* Bt = sel == 0 ? Wtq : sel == 1 ? Wtk : Wtv;
  const float* bias = sel == 0 ? bq : sel == 1 ? bk : bv;
  void* C = sel == 0 ? (void*)Qh : sel == 1 ? (void*)Kh : (void*)Vt;
  // Q pre-scaled by (1/8)*log2(e): softmax computed in exp2 domain downstream
  gemm_core(A, Bt, bias, C, sel == 0 ? 0.125f * 1.44269504088896f : 1.0f,
            sel == 2 ? 1 : 0, blk, As, Bs);
}

__global__ __launch_bounds__(256) void gemm_out(const unsigned short* __restrict__ AO,
                                                const unsigned short* __restrict__ Wto,
                                                const float* __restrict__ bo,
                                                float* __restrict__ out0) {
  __shared__ unsigned short As[128 * 64];
  __shared__ unsigned short Bs[128 * 64];
  gemm_core(AO, Wto, bo, out0, 1.0f, 2, blockIdx.x, As, Bs);
}

// ---------- attn part 1: flash (single pass, no max): row-sums, PV -> AO, 1/sum -> rrowG ----------
__global__ __launch_bounds__(256) void attn_flash(const unsigned short* __restrict__ Qh,
                                                  const unsigned short* __restrict__ Kh,
                                                  const unsigned short* __restrict__ Vt,
                                                  unsigned short* __restrict__ AO,
                                                  float* __restrict__ rrowG) {
  __shared__ float Ored[4][32][68];   // [wave][q][d], padded stride 68
  __shared__ float Ss[4][32];
  __shared__ float rrow[32];

  const int tid = threadIdx.x;
  const int l = tid & 63, w = tid >> 6;
  const int r15 = l & 15, kg = l >> 4;

  // chunked XCD swizzle: 2048 blocks = 8 x 256; 4 heads' K/V per XCD L2
  const int lb = ((int)blockIdx.x & 7) * 256 + ((int)blockIdx.x >> 3);
  const int bh = lb >> 6;
  const int q0 = (lb & 63) * 32;
  const int b = bh >> 4, h = bh & 15;

  const unsigned short* Kbase = Kh + (size_t)bh * 2048 * 64;
  const unsigned short* Vbase = Vt + (size_t)bh * 64 * 2048;

  // Q fragments (pre-scaled by 0.125*log2e): B-operand, col=q=r15, k-chunk
  bf16x8 aq[2][2];
#pragma unroll
  for (int j = 0; j < 2; ++j)
#pragma unroll
    for (int h2 = 0; h2 < 2; ++h2)
      aq[j][h2] = *(const bf16x8*)(Qh + ((size_t)bh * 2048 + q0 + j * 16 + r15) * 64 +
                                   (h2 * 4 + kg) * 8);

  const f32x4 z4 = {0.f, 0.f, 0.f, 0.f};
  float s2[2] = {0.f, 0.f};
  f32x4 oacc[2][4];
#pragma unroll
  for (int j = 0; j < 2; ++j)
#pragma unroll
    for (int d = 0; d < 4; ++d) oacc[j][d] = z4;

  const int kb0 = w * 16;
  for (int kt = 0; kt < 32; ++kt) {
    const unsigned short* kp = Kbase + (size_t)(kt * 64 + kb0 + r15) * 64;
    bf16x8 kf0 = *(const bf16x8*)(kp + kg * 8);
    bf16x8 kf1 = *(const bf16x8*)(kp + 32 + kg * 8);
    short4v vf[4];
#pragma unroll
    for (int d = 0; d < 4; ++d)
      vf[d] = *(const short4v*)(Vbase + (size_t)(d * 16 + r15) * 2048 + kt * 64 + kb0 + kg * 4);
#pragma unroll
    for (int j = 0; j < 2; ++j) {
      f32x4 sc = __builtin_amdgcn_mfma_f32_16x16x32_bf16(kf0, aq[j][0], z4, 0, 0, 0);
      sc = __builtin_amdgcn_mfma_f32_16x16x32_bf16(kf1, aq[j][1], sc, 0, 0, 0);
      float e0 = EXP2(sc[0]), e1 = EXP2(sc[1]), e2 = EXP2(sc[2]), e3 = EXP2(sc[3]);
      s2[j] += (e0 + e1) + (e2 + e3);
      short4v pf;
      pf[0] = (short)f2bf_fast(e0); pf[1] = (short)f2bf_fast(e1);
      pf[2] = (short)f2bf_fast(e2); pf[3] = (short)f2bf_fast(e3);
#pragma unroll
      for (int d = 0; d < 4; ++d)
        oacc[j][d] = __builtin_amdgcn_mfma_f32_16x16x16bf16_1k(vf[d], pf, oacc[j][d], 0, 0, 0);
    }
  }

  // reduce s2 over kg (lanes ^16, ^32), then across waves via LDS
#pragma unroll
  for (int j = 0; j < 2; ++j) {
    s2[j] += __shfl_xor(s2[j], 16, 64);
    s2[j] += __shfl_xor(s2[j], 32, 64);
    if (kg == 0) Ss[w][j * 16 + r15] = s2[j];
  }
  __syncthreads();
  if (tid < 32) {
    float s = Ss[0][tid] + Ss[1][tid] + Ss[2][tid] + Ss[3][tid];
    float rv = 1.0f / s;
    rrow[tid] = rv;
    rrowG[(size_t)bh * 2048 + q0 + tid] = rv;
  }
  __syncthreads();

  // cross-wave reduce PV partials, write AO bf16
#pragma unroll
  for (int j = 0; j < 2; ++j)
#pragma unroll
    for (int d = 0; d < 4; ++d)
      *(f32x4*)&Ored[w][j * 16 + r15][d * 16 + kg * 4] = oacc[j][d];
  __syncthreads();
  {
    int q = tid >> 3, dc = (tid & 7) * 8;
    float rv = rrow[q];
    ushort8v o;
#pragma unroll
    for (int i = 0; i < 8; ++i) {
      float s = Ored[0][q][dc + i] + Ored[1][q][dc + i] + Ored[2][q][dc + i] + Ored[3][q][dc + i];
      o[i] = f2bf(s * rv);
    }
    *(ushort8v*)(AO + ((size_t)(b * 2048 + q0 + q)) * 1024 + h * 64 + dc) = o;
  }
}

// ---------- attn part 2: attn-matrix writer with fill-like stores ----------
// Per wave: 16 q-rows, k in 64-wide chunks. Scores -> exp2(+log2(1/sum)) -> wave-private
// LDS tile (16x64 f32, XOR-swizzled) -> streamed out as 4 stores/chunk, each 1KB:
// 4 rows x 256B contiguous, every 128B line fully covered by ONE instruction.
// K loads double-buffered one chunk ahead, issued BEFORE the previous chunk's
// stores, so in-order vmcnt retirement never couples load-waits to stores.
__global__ __launch_bounds__(256) void attn_write(const unsigned short* __restrict__ Qh,
                                                  const unsigned short* __restrict__ Kh,
                                                  const float* __restrict__ rrowG,
                                                  float* __restrict__ attnO) {
  __shared__ float S[4][16][72];   // per-wave 16q x 64k tile, row stride 72

  const int tid = threadIdx.x;
  const int l = tid & 63, w = tid >> 6;
  const int r15 = l & 15, kg = l >> 4;

  // grid 1024 = 32 bh x 32 q-tiles(64 rows); XCD chunked swizzle (128 lb/XCD)
  const int lb = ((int)blockIdx.x & 7) * 128 + ((int)blockIdx.x >> 3);
  const int bh = lb >> 5;
  const int q0 = (lb & 31) * 64 + w * 16;   // this wave's 16 q rows

  const unsigned short* Kbase = Kh + (size_t)bh * 2048 * 64;
  const unsigned short* Qp = Qh + ((size_t)bh * 2048 + q0 + r15) * 64;
  bf16x8 aq0 = *(const bf16x8*)(Qp + kg * 8);
  bf16x8 aq1 = *(const bf16x8*)(Qp + 32 + kg * 8);

  // fold 1/sum into exp2 argument: exp2(sc)*rv == exp2(sc + log2(rv))
  const float lrv = __log2f(rrowG[(size_t)bh * 2048 + q0 + r15]);

  float* Sw = &S[w][0][0];
  float* attnBase = attnO + ((size_t)bh * 2048 + q0) * 2048;
  const f32x4 z4 = {0.f, 0.f, 0.f, 0.f};

  bf16x8 ka[4][2], kb[4][2];

#define LOADK(KF, c)                                                              \
  {                                                                               \
    const unsigned short* kp_ = Kbase + (size_t)((c) * 64 + r15) * 64 + kg * 8;   \
    _Pragma("unroll")                                                             \
    for (int sub = 0; sub < 4; ++sub) {                                           \
      KF[sub][0] = *(const bf16x8*)(kp_ + sub * 16 * 64);                         \
      KF[sub][1] = *(const bf16x8*)(kp_ + sub * 16 * 64 + 32);                    \
    }                                                                             \
  }

#define PROCESS(KF, c)                                                            \
  {                                                                               \
    _Pragma("unroll")                                                             \
    for (int sub = 0; sub < 4; ++sub) {                                           \
      f32x4 sc = __builtin_amdgcn_mfma_f32_16x16x32_bf16(KF[sub][0], aq0, z4, 0, 0, 0); \
      sc = __builtin_amdgcn_mfma_f32_16x16x32_bf16(KF[sub][1], aq1, sc, 0, 0, 0); \
      f32x4 st = {EXP2(sc[0] + lrv), EXP2(sc[1] + lrv),                           \
                  EXP2(sc[2] + lrv), EXP2(sc[3] + lrv)};                          \
      int col = (sub * 16 + kg * 4) ^ ((r15 & 3) << 4);                           \
      *(f32x4*)(Sw + r15 * 72 + col) = st;                                        \
    }                                                                             \
    _Pragma("unroll")                                                             \
    for (int s = 0; s < 4; ++s) {                                                 \
      int qr = 4 * s + (l >> 4);                                                  \
      int ci = 4 * (l & 15);                                                      \
      int scol = ci ^ ((qr & 3) << 4);                                            \
      f32x4 v = *(const f32x4*)(Sw + qr * 72 + scol);                             \
      *(f32x4*)(attnBase + (size_t)qr * 2048 + (c) * 64 + ci) = v;                \
    }                                                                             \
  }

  LOADK(ka, 0)
  for (int c = 0; c < 32; c += 2) {
    LOADK(kb, c + 1)
    PROCESS(ka, c)
    if (c + 2 < 32) LOADK(ka, c + 2)
    PROCESS(kb, c + 1)
  }
#undef LOADK
#undef PROCESS
}

extern "C" void kernel_launch(void* const* d_in, const int* in_sizes, int n_in,
                              void* d_out, int out_size, void* d_ws, size_t ws_size,
                              hipStream_t stream) {
  const float* q  = (const float*)d_in[0];
  const float* k  = (const float*)d_in[1];
  const float* v  = (const float*)d_in[2];
  const float* Wq = (const float*)d_in[3];
  const float* bq = (const float*)d_in[4];
  const float* Wk = (const float*)d_in[5];
  const float* bk = (const float*)d_in[6];
  const float* Wv = (const float*)d_in[7];
  const float* bvp = (const float*)d_in[8];
  const float* Wo = (const float*)d_in[9];
  const float* bo = (const float*)d_in[10];

  char* wsb = (char*)d_ws;
  const size_t MB = (size_t)1 << 20;
  unsigned short* qb  = (unsigned short*)(wsb + 0 * MB);
  unsigned short* kbp = (unsigned short*)(wsb + 8 * MB);
  unsigned short* vbp = (unsigned short*)(wsb + 16 * MB);
  unsigned short* Wtq = (unsigned short*)(wsb + 24 * MB);
  unsigned short* Wtk = (unsigned short*)(wsb + 26 * MB);
  unsigned short* Wtv = (unsigned short*)(wsb + 28 * MB);
  unsigned short* Wto = (unsigned short*)(wsb + 30 * MB);
  unsigned short* Qh  = (unsigned short*)(wsb + 32 * MB);
  unsigned short* Kh  = (unsigned short*)(wsb + 40 * MB);
  unsigned short* Vt  = (unsigned short*)(wsb + 48 * MB);
  unsigned short* AO  = (unsigned short*)(wsb + 56 * MB);
  // rrowG reuses the qb region (qb is dead after gemm_qkv; rewritten each launch)
  float* rrowG = (float*)(wsb + 0 * MB);

  float* attnO = (float*)d_out + (size_t)2 * 2048 * 1024;

  cvt_qkv<<<dim3(4096, 3), 256, 0, stream>>>(q, k, v, qb, kbp, vbp);
  transpose_all<<<1024, 256, 0, stream>>>(Wq, Wk, Wv, Wo, Wtq, Wtk, Wtv, Wto);
  gemm_qkv<<<768, 256, 0, stream>>>(qb, kbp, vbp, Wtq, Wtk, Wtv, bq, bk, bvp, Qh, Kh, Vt);
  attn_flash<<<2048, 256, 0, stream>>>(Qh, Kh, Vt, AO, rrowG);
  attn_write<<<1024, 256, 0, stream>>>(Qh, Kh, rrowG, attnO);
  gemm_out<<<256, 256, 0, stream>>>(AO, Wto, bo, (float*)d_out);
}

// Round 7
// 412.660 us; speedup vs baseline: 1.0915x; 1.0915x over previous
//
#include <hip/hip_runtime.h>
#include <hip/hip_bf16.h>

typedef __bf16 bf16x8 __attribute__((ext_vector_type(8)));
typedef float f32x4 __attribute__((ext_vector_type(4)));
typedef short short4v __attribute__((ext_vector_type(4)));
typedef unsigned short ushort8v __attribute__((ext_vector_type(8)));

#define DEV static __device__ __forceinline__

#if __has_builtin(__builtin_amdgcn_exp2f)
#define EXP2(x) __builtin_amdgcn_exp2f(x)
#else
#define EXP2(x) exp2f(x)
#endif

DEV unsigned short f2bf(float x) {
  union { __hip_bfloat16 b; unsigned short u; } c;
  c.b = __float2bfloat16(x);
  return c.u;
}

// fast RNE f32->bf16 (inputs are finite; no NaN path needed)
DEV unsigned f2bf_fast_u(float x) {
  union { float f; unsigned u; } c;
  c.f = x;
  return (c.u + 0x7fff + ((c.u >> 16) & 1)) >> 16;
}
DEV unsigned short f2bf_fast(float x) { return (unsigned short)f2bf_fast_u(x); }

DEV void gload_lds16(const void* g, void* l) {
  __builtin_amdgcn_global_load_lds((const __attribute__((address_space(1))) void*)g,
                                   (__attribute__((address_space(3))) void*)l, 16, 0, 0);
}

// ---------- convert q/k/v fp32 -> bf16 ----------
__global__ __launch_bounds__(256) void cvt_qkv(const float* __restrict__ q,
                                               const float* __restrict__ k,
                                               const float* __restrict__ v,
                                               unsigned short* __restrict__ qb,
                                               unsigned short* __restrict__ kb,
                                               unsigned short* __restrict__ vb) {
  const float* src = blockIdx.y == 0 ? q : (blockIdx.y == 1 ? k : v);
  unsigned short* dst = blockIdx.y == 0 ? qb : (blockIdx.y == 1 ? kb : vb);
  int idx = (blockIdx.x * 256 + threadIdx.x) * 4;
  float4 xv = *(const float4*)(src + idx);
  ushort4 o;
  o.x = f2bf(xv.x); o.y = f2bf(xv.y); o.z = f2bf(xv.z); o.w = f2bf(xv.w);
  *(ushort4*)(dst + idx) = o;
}

// ---------- transpose 4x 1024x1024 weight fp32 -> bf16 (Wt[n][k] = W[k][n]) ----------
__global__ __launch_bounds__(256) void transpose_all(const float* __restrict__ W0,
                                                     const float* __restrict__ W1,
                                                     const float* __restrict__ W2,
                                                     const float* __restrict__ W3,
                                                     unsigned short* __restrict__ T0,
                                                     unsigned short* __restrict__ T1,
                                                     unsigned short* __restrict__ T2,
                                                     unsigned short* __restrict__ T3) {
  __shared__ float t[64][68];
  int sel = blockIdx.x >> 8;
  const float* W = sel == 0 ? W0 : sel == 1 ? W1 : sel == 2 ? W2 : W3;
  unsigned short* Wt = sel == 0 ? T0 : sel == 1 ? T1 : sel == 2 ? T2 : T3;
  int tile = blockIdx.x & 255;
  int tr = tile >> 4, tc = tile & 15;
  int lr = threadIdx.x >> 4, lc4 = threadIdx.x & 15;
#pragma unroll
  for (int i = 0; i < 4; ++i) {
    int r = i * 16 + lr;
    float4 v = *(const float4*)(W + (size_t)(tr * 64 + r) * 1024 + tc * 64 + lc4 * 4);
    t[r][lc4 * 4 + 0] = v.x; t[r][lc4 * 4 + 1] = v.y;
    t[r][lc4 * 4 + 2] = v.z; t[r][lc4 * 4 + 3] = v.w;
  }
  __syncthreads();
#pragma unroll
  for (int i = 0; i < 4; ++i) {
    int r = i * 16 + lr;
    ushort4 o;
    o.x = f2bf(t[lc4 * 4 + 0][r]);
    o.y = f2bf(t[lc4 * 4 + 1][r]);
    o.z = f2bf(t[lc4 * 4 + 2][r]);
    o.w = f2bf(t[lc4 * 4 + 3][r]);
    *(ushort4*)(Wt + (size_t)(tc * 64 + r) * 1024 + tr * 64 + lc4 * 4) = o;
  }
}

// ---------- GEMM core: C[4096,1024] = A[4096,1024] @ Bt[1024,1024]^T + bias, *scale ----------
DEV void gemm_core(const unsigned short* __restrict__ A, const unsigned short* __restrict__ Bt,
                   const float* __restrict__ bias, void* __restrict__ Cout,
                   float scale, int mode, int blk,
                   unsigned short* As, unsigned short* Bs) {
  const int tid = threadIdx.x;
  const int l = tid & 63, w = tid >> 6;
  const int wm = w >> 1, wn = w & 1;
  const int r15 = l & 15, kg = l >> 4;
  const int mt = blk >> 3, nt = blk & 7;

  const f32x4 fz = {0.f, 0.f, 0.f, 0.f};
  f32x4 acc[4][4];
#pragma unroll
  for (int i = 0; i < 4; ++i)
#pragma unroll
    for (int j = 0; j < 4; ++j) acc[i][j] = fz;

  for (int kt = 0; kt < 16; ++kt) {
#pragma unroll
    for (int c = 0; c < 4; ++c) {
      int chunk = c * 256 + tid;
      int row = chunk >> 3, slot = chunk & 7;
      int gsl = slot ^ (row & 7);
      gload_lds16(A + (size_t)(mt * 128 + row) * 1024 + kt * 64 + gsl * 8, As + chunk * 8);
      gload_lds16(Bt + (size_t)(nt * 128 + row) * 1024 + kt * 64 + gsl * 8, Bs + chunk * 8);
    }
    __syncthreads();
#pragma unroll
    for (int ks = 0; ks < 2; ++ks) {
      bf16x8 a[4], b[4];
      int slot = ks * 4 + kg;
#pragma unroll
      for (int i = 0; i < 4; ++i) {
        int ra = wm * 64 + i * 16 + r15;
        a[i] = *(const bf16x8*)(As + ra * 64 + (slot ^ (ra & 7)) * 8);
        int rb = wn * 64 + i * 16 + r15;
        b[i] = *(const bf16x8*)(Bs + rb * 64 + (slot ^ (rb & 7)) * 8);
      }
#pragma unroll
      for (int i = 0; i < 4; ++i)
#pragma unroll
        for (int j = 0; j < 4; ++j)
          acc[i][j] = __builtin_amdgcn_mfma_f32_16x16x32_bf16(a[i], b[j], acc[i][j], 0, 0, 0);
    }
    __syncthreads();
  }

#pragma unroll
  for (int j = 0; j < 4; ++j) {
    int gc = nt * 128 + wn * 64 + j * 16 + r15;
    float bj = bias[gc];
#pragma unroll
    for (int i = 0; i < 4; ++i) {
#pragma unroll
      for (int r = 0; r < 4; ++r) {
        int gr = mt * 128 + wm * 64 + i * 16 + kg * 4 + r;
        float val = (acc[i][j][r] + bj) * scale;
        if (mode == 2) {
          ((float*)Cout)[(size_t)gr * 1024 + gc] = val;
        } else {
          int bb = gr >> 11, s = gr & 2047, hh = gc >> 6, dk = gc & 63;
          if (mode == 0)
            ((unsigned short*)Cout)[((size_t)(bb * 16 + hh) * 2048 + s) * 64 + dk] = f2bf(val);
          else
            ((unsigned short*)Cout)[((size_t)(bb * 16 + hh) * 64 + dk) * 2048 + s] = f2bf(val);
        }
      }
    }
  }
}

__global__ __launch_bounds__(256) void gemm_qkv(const unsigned short* __restrict__ qb,
                                                const unsigned short* __restrict__ kb,
                                                const unsigned short* __restrict__ vb,
                                                const unsigned short* __restrict__ Wtq,
                                                const unsigned short* __restrict__ Wtk,
                                                const unsigned short* __restrict__ Wtv,
                                                const float* __restrict__ bq,
                                                const float* __restrict__ bk,
                                                const float* __restrict__ bv,
                                                unsigned short* __restrict__ Qh,
                                                unsigned short* __restrict__ Kh,
                                                unsigned short* __restrict__ Vt) {
  __shared__ unsigned short As[128 * 64];
  __shared__ unsigned short Bs[128 * 64];
  int sel = blockIdx.x >> 8, blk = blockIdx.x & 255;
  const unsigned short* A = sel == 0 ? qb : sel == 1 ? kb : vb;
  const unsigned short* Bt = sel == 0 ? Wtq : sel == 1 ? Wtk : Wtv;
  const float* bias = sel == 0 ? bq : sel == 1 ? bk : bv;
  void* C = sel == 0 ? (void*)Qh : sel == 1 ? (void*)Kh : (void*)Vt;
  // Q pre-scaled by (1/8)*log2(e): softmax computed in exp2 domain downstream
  gemm_core(A, Bt, bias, C, sel == 0 ? 0.125f * 1.44269504088896f : 1.0f,
            sel == 2 ? 1 : 0, blk, As, Bs);
}

__global__ __launch_bounds__(256) void gemm_out(const unsigned short* __restrict__ AO,
                                                const unsigned short* __restrict__ Wto,
                                                const float* __restrict__ bo,
                                                float* __restrict__ out0) {
  __shared__ unsigned short As[128 * 64];
  __shared__ unsigned short Bs[128 * 64];
  gemm_core(AO, Wto, bo, out0, 1.0f, 2, blockIdx.x, As, Bs);
}

// ---------- attn part 1: flash (single pass, no max): row-sums, PV -> AO, 1/sum -> rrowG ----------
__global__ __launch_bounds__(256) void attn_flash(const unsigned short* __restrict__ Qh,
                                                  const unsigned short* __restrict__ Kh,
                                                  const unsigned short* __restrict__ Vt,
                                                  unsigned short* __restrict__ AO,
                                                  float* __restrict__ rrowG) {
  __shared__ float Ored[4][32][68];   // [wave][q][d], padded stride 68
  __shared__ float Ss[4][32];
  __shared__ float rrow[32];

  const int tid = threadIdx.x;
  const int l = tid & 63, w = tid >> 6;
  const int r15 = l & 15, kg = l >> 4;

  // chunked XCD swizzle: 2048 blocks = 8 x 256; 4 heads' K/V per XCD L2
  const int lb = ((int)blockIdx.x & 7) * 256 + ((int)blockIdx.x >> 3);
  const int bh = lb >> 6;
  const int q0 = (lb & 63) * 32;
  const int b = bh >> 4, h = bh & 15;

  const unsigned short* Kbase = Kh + (size_t)bh * 2048 * 64;
  const unsigned short* Vbase = Vt + (size_t)bh * 64 * 2048;

  // Q fragments (pre-scaled by 0.125*log2e): B-operand, col=q=r15, k-chunk
  bf16x8 aq[2][2];
#pragma unroll
  for (int j = 0; j < 2; ++j)
#pragma unroll
    for (int h2 = 0; h2 < 2; ++h2)
      aq[j][h2] = *(const bf16x8*)(Qh + ((size_t)bh * 2048 + q0 + j * 16 + r15) * 64 +
                                   (h2 * 4 + kg) * 8);

  const f32x4 z4 = {0.f, 0.f, 0.f, 0.f};
  float s2[2] = {0.f, 0.f};
  f32x4 oacc[2][4];
#pragma unroll
  for (int j = 0; j < 2; ++j)
#pragma unroll
    for (int d = 0; d < 4; ++d) oacc[j][d] = z4;

  const int kb0 = w * 16;
  for (int kt = 0; kt < 32; ++kt) {
    const unsigned short* kp = Kbase + (size_t)(kt * 64 + kb0 + r15) * 64;
    bf16x8 kf0 = *(const bf16x8*)(kp + kg * 8);
    bf16x8 kf1 = *(const bf16x8*)(kp + 32 + kg * 8);
    short4v vf[4];
#pragma unroll
    for (int d = 0; d < 4; ++d)
      vf[d] = *(const short4v*)(Vbase + (size_t)(d * 16 + r15) * 2048 + kt * 64 + kb0 + kg * 4);
#pragma unroll
    for (int j = 0; j < 2; ++j) {
      f32x4 sc = __builtin_amdgcn_mfma_f32_16x16x32_bf16(kf0, aq[j][0], z4, 0, 0, 0);
      sc = __builtin_amdgcn_mfma_f32_16x16x32_bf16(kf1, aq[j][1], sc, 0, 0, 0);
      float e0 = EXP2(sc[0]), e1 = EXP2(sc[1]), e2 = EXP2(sc[2]), e3 = EXP2(sc[3]);
      s2[j] += (e0 + e1) + (e2 + e3);
      short4v pf;
      pf[0] = (short)f2bf_fast(e0); pf[1] = (short)f2bf_fast(e1);
      pf[2] = (short)f2bf_fast(e2); pf[3] = (short)f2bf_fast(e3);
#pragma unroll
      for (int d = 0; d < 4; ++d)
        oacc[j][d] = __builtin_amdgcn_mfma_f32_16x16x16bf16_1k(vf[d], pf, oacc[j][d], 0, 0, 0);
    }
  }

  // reduce s2 over kg (lanes ^16, ^32), then across waves via LDS
#pragma unroll
  for (int j = 0; j < 2; ++j) {
    s2[j] += __shfl_xor(s2[j], 16, 64);
    s2[j] += __shfl_xor(s2[j], 32, 64);
    if (kg == 0) Ss[w][j * 16 + r15] = s2[j];
  }
  __syncthreads();
  if (tid < 32) {
    float s = Ss[0][tid] + Ss[1][tid] + Ss[2][tid] + Ss[3][tid];
    float rv = 1.0f / s;
    rrow[tid] = rv;
    rrowG[(size_t)bh * 2048 + q0 + tid] = rv;
  }
  __syncthreads();

  // cross-wave reduce PV partials, write AO bf16
#pragma unroll
  for (int j = 0; j < 2; ++j)
#pragma unroll
    for (int d = 0; d < 4; ++d)
      *(f32x4*)&Ored[w][j * 16 + r15][d * 16 + kg * 4] = oacc[j][d];
  __syncthreads();
  {
    int q = tid >> 3, dc = (tid & 7) * 8;
    float rv = rrow[q];
    ushort8v o;
#pragma unroll
    for (int i = 0; i < 8; ++i) {
      float s = Ored[0][q][dc + i] + Ored[1][q][dc + i] + Ored[2][q][dc + i] + Ored[3][q][dc + i];
      o[i] = f2bf(s * rv);
    }
    *(ushort8v*)(AO + ((size_t)(b * 2048 + q0 + q)) * 1024 + h * 64 + dc) = o;
  }
}

// ---------- attn part 2: attn-matrix writer, dense sequential streaming ----------
// Per wg: 16 q-rows (a 128KB CONTIGUOUS output region: row stride == row size).
// Phase 1 (compute): wave w fills k-quarter [w*512, w*512+512) of a shared
//   16x2048 bf16 LDS tile (XOR-swizzled rows): swapped QK^T -> exp2(sc+log2(1/sum))
//   -> packed bf16. Loads are the only VMEM here.
// Phase 2 (stream): after one barrier, wave w expands bf16->f32 and stores its
//   4 consecutive rows = 32KB in strictly ascending address order; stores are the
//   only VMEM in the wave. 64KB LDS -> 2 wg/CU, so one wg streams while the
//   other computes. This matches the fillBuffer access pattern (DRAM page hits).
__global__ __launch_bounds__(256) void attn_write(const unsigned short* __restrict__ Qh,
                                                  const unsigned short* __restrict__ Kh,
                                                  const float* __restrict__ rrowG,
                                                  float* __restrict__ attnO) {
  __shared__ unsigned short Pl[16 * 2048];   // 64 KB, row stride 4096 B, 16B-granule XOR swizzle

  const int tid = threadIdx.x;
  const int l = tid & 63, w = tid >> 6;
  const int r15 = l & 15, kg = l >> 4;

  // grid 4096 = 32 bh x 128 q-tiles(16 rows); XCD chunked swizzle (512 lb/XCD = 4 heads)
  const int lb = ((int)blockIdx.x & 7) * 512 + ((int)blockIdx.x >> 3);
  const int bh = lb >> 7;
  const int q0 = (lb & 127) * 16;

  const unsigned short* Kbase = Kh + (size_t)bh * 2048 * 64;
  const unsigned short* Qp = Qh + ((size_t)bh * 2048 + q0 + r15) * 64;
  bf16x8 aq0 = *(const bf16x8*)(Qp + kg * 8);
  bf16x8 aq1 = *(const bf16x8*)(Qp + 32 + kg * 8);

  // fold 1/sum into exp2 argument: exp2(sc)*rv == exp2(sc + log2(rv))
  const float lrv = __log2f(rrowG[(size_t)bh * 2048 + q0 + r15]);

  const f32x4 z4 = {0.f, 0.f, 0.f, 0.f};
  const int kq = w * 512;              // this wave's k-quarter
  char* Plb = (char*)Pl;

  bf16x8 ka[4][2], kb[4][2];

#define LOADK(KF, c)                                                              \
  {                                                                               \
    const unsigned short* kp_ = Kbase + (size_t)(kq + (c) * 64 + r15) * 64 + kg * 8; \
    _Pragma("unroll")                                                             \
    for (int sub = 0; sub < 4; ++sub) {                                           \
      KF[sub][0] = *(const bf16x8*)(kp_ + sub * 16 * 64);                         \
      KF[sub][1] = *(const bf16x8*)(kp_ + sub * 16 * 64 + 32);                    \
    }                                                                             \
  }

#define PROCESS(KF, c)                                                            \
  {                                                                               \
    _Pragma("unroll")                                                             \
    for (int sub = 0; sub < 4; ++sub) {                                           \
      f32x4 sc = __builtin_amdgcn_mfma_f32_16x16x32_bf16(KF[sub][0], aq0, z4, 0, 0, 0); \
      sc = __builtin_amdgcn_mfma_f32_16x16x32_bf16(KF[sub][1], aq1, sc, 0, 0, 0); \
      unsigned u0 = f2bf_fast_u(EXP2(sc[0] + lrv)) | (f2bf_fast_u(EXP2(sc[1] + lrv)) << 16); \
      unsigned u1 = f2bf_fast_u(EXP2(sc[2] + lrv)) | (f2bf_fast_u(EXP2(sc[3] + lrv)) << 16); \
      int colb = (kq + (c) * 64 + sub * 16 + kg * 4) * 2;                         \
      uint2 uu = {u0, u1};                                                        \
      *(uint2*)(Plb + r15 * 4096 + (colb ^ ((r15 & 7) << 4))) = uu;               \
    }                                                                             \
  }

  LOADK(ka, 0)
  for (int c = 0; c < 8; c += 2) {
    LOADK(kb, c + 1)
    PROCESS(ka, c)
    if (c + 2 < 8) LOADK(ka, c + 2)
    PROCESS(kb, c + 1)
  }
#undef LOADK
#undef PROCESS

  __syncthreads();

  // phase 2: stream 4 consecutive rows per wave, ascending addresses, stores only
  float* wavep = attnO + ((size_t)bh * 2048 + q0 + w * 4) * 2048;
#pragma unroll
  for (int ri = 0; ri < 4; ++ri) {
    int qr = w * 4 + ri;
    const char* rowl = Plb + qr * 4096;
    int swz = (qr & 7) << 4;
    float* rowp = wavep + (size_t)ri * 2048 + l * 4;
#pragma unroll
    for (int seg = 0; seg < 8; ++seg) {
      uint2 u = *(const uint2*)(rowl + ((seg * 512 + l * 8) ^ swz));
      union { unsigned u; float f; } c0, c1, c2, c3;
      c0.u = u.x << 16; c1.u = u.x & 0xffff0000u;
      c2.u = u.y << 16; c3.u = u.y & 0xffff0000u;
      f32x4 v = {c0.f, c1.f, c2.f, c3.f};
      __builtin_nontemporal_store(v, (f32x4*)(rowp + seg * 256));
    }
  }
}

extern "C" void kernel_launch(void* const* d_in, const int* in_sizes, int n_in,
                              void* d_out, int out_size, void* d_ws, size_t ws_size,
                              hipStream_t stream) {
  const float* q  = (const float*)d_in[0];
  const float* k  = (const float*)d_in[1];
  const float* v  = (const float*)d_in[2];
  const float* Wq = (const float*)d_in[3];
  const float* bq = (const float*)d_in[4];
  const float* Wk = (const float*)d_in[5];
  const float* bk = (const float*)d_in[6];
  const float* Wv = (const float*)d_in[7];
  const float* bvp = (const float*)d_in[8];
  const float* Wo = (const float*)d_in[9];
  const float* bo = (const float*)d_in[10];

  char* wsb = (char*)d_ws;
  const size_t MB = (size_t)1 << 20;
  unsigned short* qb  = (unsigned short*)(wsb + 0 * MB);
  unsigned short* kbp = (unsigned short*)(wsb + 8 * MB);
  unsigned short* vbp = (unsigned short*)(wsb + 16 * MB);
  unsigned short* Wtq = (unsigned short*)(wsb + 24 * MB);
  unsigned short* Wtk = (unsigned short*)(wsb + 26 * MB);
  unsigned short* Wtv = (unsigned short*)(wsb + 28 * MB);
  unsigned short* Wto = (unsigned short*)(wsb + 30 * MB);
  unsigned short* Qh  = (unsigned short*)(wsb + 32 * MB);
  unsigned short* Kh  = (unsigned short*)(wsb + 40 * MB);
  unsigned short* Vt  = (unsigned short*)(wsb + 48 * MB);
  unsigned short* AO  = (unsigned short*)(wsb + 56 * MB);
  // rrowG reuses the qb region (qb is dead after gemm_qkv; rewritten each launch)
  float* rrowG = (float*)(wsb + 0 * MB);

  float* attnO = (float*)d_out + (size_t)2 * 2048 * 1024;

  cvt_qkv<<<dim3(4096, 3), 256, 0, stream>>>(q, k, v, qb, kbp, vbp);
  transpose_all<<<1024, 256, 0, stream>>>(Wq, Wk, Wv, Wo, Wtq, Wtk, Wtv, Wto);
  gemm_qkv<<<768, 256, 0, stream>>>(qb, kbp, vbp, Wtq, Wtk, Wtv, bq, bk, bvp, Qh, Kh, Vt);
  attn_flash<<<2048, 256, 0, stream>>>(Qh, Kh, Vt, AO, rrowG);
  attn_write<<<4096, 256, 0, stream>>>(Qh, Kh, rrowG, attnO);
  gemm_out<<<256, 256, 0, stream>>>(AO, Wto, bo, (float*)d_out);
}